// Round 18
// baseline (1428.679 us; speedup 1.0000x reference)
//
#include <hip/hip_runtime.h>
#include <hip/hip_bf16.h>
#include <hip/hip_cooperative_groups.h>

namespace cg = cooperative_groups;

// CRF-as-RNN mean-field on MI355X. B=2, L=21, C=3, H=W=96, N=9216, NITERS=5.
//
// Accum structure = R12 champion (5 post-R12 structural experiments all
// regressed; VALUBusy 75% + LDS-pipe model ~57us => structural optimum):
// no W tile — each lane generates its own A-fragment in registers; FS
// staged to LDS (1KB) read via conflict-free broadcast ds_read_b128 (XOR
// slot swizzle); M tile XOR-swizzled zero-conflict, const rows 21..31
// (row 21 = 1.0 -> MFMA col 21 = rowsum(W) free); FS+M double-buffered,
// ONE thin lgkm-only barrier per tile; depth-1 prefetch.
// THIS ROUND: the ~73us OUTSIDE k_accum (7 thread-starved small launches +
// 11 inter-kernel drain gaps) is replaced by ONE cooperative kernel with
// grid.sync() phase boundaries. S=3 -> 864 blocks, guaranteed co-resident
// (29KB LDS -> 5 blocks/CU max active, 1280 >= 864; VGPR ~60 <= 102).
// Fallback to separate-kernel launches if cooperative launch errors.
// msg = P/P[21]; Q = softmax_l(-(E0+msg)); MQ = Mu@Q (bf16).
//
// (R17 bench was a GPUAcquisitionTimeout; this is an unchanged resubmit.)

#define BB 2
#define LL 21
#define LP (LL + 1)   // Ppart rows: 21 msg cols + 1 rowsum col
#define NNPX 9216
#define NITERS 5
#define SSPLIT 3      // m-splits; grid = 288*SSPLIT = 864 (co-residency safe)
#define TT (144 / SSPLIT)
#define LOG2E 1.4426950408889634f
#define INVL2E 0.6931471805599453f

// raw barrier: waits LDS ops of this wave, syncs, does NOT drain vmcnt
#define BARRIER() asm volatile("s_waitcnt lgkmcnt(0)\n\ts_barrier" ::: "memory")

typedef __attribute__((ext_vector_type(8))) short short8;
typedef __attribute__((ext_vector_type(4))) float f32x4;
typedef __attribute__((ext_vector_type(4))) unsigned int u32x4;

static __device__ inline unsigned int pk_bf16(float a, float b) {
    __hip_bfloat162 h = __float22bfloat162_rn(make_float2(a, b));
    unsigned int u;
    __builtin_memcpy(&u, &h, 4);
    return u;
}

// ---------------- prep body: FS + Q0 + MQ0(bf16), 4 waves / 64 px ----------
static __device__ void prep_body(
        int rb, int t,
        const float* __restrict__ E0, const float* __restrict__ Refs,
        const float* __restrict__ Mu,
        float4* __restrict__ FS, __hip_bfloat16* __restrict__ MQ) {
    __shared__ float muS_p[LL * LL];
    __shared__ float red1_p[4][64], red2_p[4][64];
    __shared__ float Qs_p[LL][64];

    for (int i = t; i < LL * LL; i += 256) muS_p[i] = Mu[i];

    int q = t >> 6, px = t & 63;
    int pid = rb * 64 + px;                  // b*N + n (64-tiles never cross b)
    int b = pid / NNPX, n = pid % NNPX;

    if (q == 0) {  // FS: one lane per pixel, coalesced
        const float* rbp = Refs + (size_t)b * 3 * NNPX + n;
        float r0 = rbp[0], r1 = rbp[NNPX], r2 = rbp[2 * NNPX];
        float g = -0.5f * (r0 * r0 + r1 * r1 + r2 * r2);
        FS[pid] = make_float4(g * LOG2E, r0 * LOG2E, r1 * LOG2E, r2 * LOG2E);
    }

    int l0 = q * 6;
    const float* eb = E0 + (size_t)b * LL * NNPX + n;
    float x[6];
    float mx = -1e30f;
    #pragma unroll
    for (int i = 0; i < 6; ++i) {
        int l = l0 + i;
        x[i] = (l < LL) ? -eb[(size_t)l * NNPX] : -1e30f;
        mx = fmaxf(mx, x[i]);
    }
    red1_p[q][px] = mx;
    __syncthreads();
    mx = fmaxf(fmaxf(red1_p[0][px], red1_p[1][px]), fmaxf(red1_p[2][px], red1_p[3][px]));
    float s = 0.f;
    #pragma unroll
    for (int i = 0; i < 6; ++i) { x[i] = __builtin_amdgcn_exp2f((x[i] - mx) * LOG2E); s += x[i]; }
    red2_p[q][px] = s;
    __syncthreads();
    float rs = __builtin_amdgcn_rcpf(red2_p[0][px] + red2_p[1][px] + red2_p[2][px] + red2_p[3][px]);
    #pragma unroll
    for (int i = 0; i < 6; ++i) if (l0 + i < LL) Qs_p[l0 + i][px] = x[i] * rs;
    __syncthreads();

    __hip_bfloat16* mq = MQ + (size_t)b * LL * NNPX + n;
    #pragma unroll
    for (int j = 0; j < 6; ++j) {
        int k = l0 + j;
        if (k < LL) {
            float a = 0.f;
            for (int l = 0; l < LL; ++l) a += muS_p[k * LL + l] * Qs_p[l][px];
            mq[(size_t)k * NNPX] = __float2bfloat16(a);
        }
    }
}

// ---------------- accum body (R12 champion, T=48) ----------------
static __device__ void accum_body(
        int rb, int s, int t,
        const float4* __restrict__ FS, const unsigned int* __restrict__ MQbf,
        float* __restrict__ Ppart) {
    __shared__ __align__(16) float FSlds[2][256];
    __shared__ __align__(16) unsigned short Mlds[2][32 * 64];

    int b  = rb / 144;
    int n0 = (rb % 144) * 64;
    int wv = t >> 6, lane = t & 63;
    int lr = lane & 15, g = lane >> 4;

    // init constant B rows in BOTH buffers (cheap; re-done every phase)
    for (int i = t; i < 11 * 32 * 2; i += 256) {
        int bufi = i >= 11 * 32;
        int ii = i - bufi * 11 * 32;
        int r = 21 + (ii >> 5), d = ii & 31;
        ((unsigned int*)&Mlds[bufi][r * 64])[d] = (r == 21) ? 0x3F803F80u : 0u;
    }

    // this thread's A-row feature (row = wv*16 + lr), derived from FS
    int row = wv * 16 + lr;
    float4 fv = FS[(size_t)b * NNPX + n0 + row];
    float fnx = fv.y * INVL2E, fny = fv.z * INVL2E, fnz = fv.w * INVL2E;

    const int t0 = s * TT;
    const float* fs32 = (const float*)(FS + (size_t)b * NNPX);
    const unsigned int* mqb = MQbf + (size_t)b * LL * (NNPX / 2);

    // FS stage: thread t loads global dword (m0*4 + t) -> swizzled LDS dword
    int mloc = t >> 2, comp = t & 3;
    int fslot = (mloc & ~7) | ((mloc ^ (mloc >> 3)) & 7);
    int fsw = fslot * 4 + comp;

    // MQ stage ownership (3 dwords) + swizzled dests
    int sl0 = t >> 5, sm0 = t & 31;
    int sl1 = (t + 256) >> 5, sm1 = (t + 256) & 31;
    int sl2 = (t + 512) >> 5, sm2 = (t + 512) & 31;   // valid iff t<160
    int mw0 = sl0 * 32 + (((sm0 >> 2) ^ (sl0 & 7)) << 2) + (sm0 & 3);
    int mw1 = sl1 * 32 + (((sm1 >> 2) ^ (sl1 & 7)) << 2) + (sm1 & 3);
    int mw2 = sl2 * 32 + (((sm2 >> 2) ^ (sl2 & 7)) << 2) + (sm2 & 3);

    // B-frag read offsets (zero-conflict)
    int ib0 = lr * 64 + ((g ^ (lr & 7)) << 3);
    int ib1 = lr * 64 + (((g + 4) ^ (lr & 7)) << 3);
    int ib2 = (16 + lr) * 64 + ((g ^ (lr & 7)) << 3);
    int ib3 = (16 + lr) * 64 + (((g + 4) ^ (lr & 7)) << 3);

    f32x4 acc0 = {0.f, 0.f, 0.f, 0.f};   // C cols 0..15
    f32x4 acc1 = {0.f, 0.f, 0.f, 0.f};   // C cols 16..21 (22..31 discarded)

    int g8 = g * 8;

    float fsr;
    unsigned int mrA0, mrA1, mrA2;

    auto LOAD = [&](int tile) {
        int m0 = (t0 + tile) * 64;
        fsr = fs32[m0 * 4 + t];
        int mo0 = (t0 + tile) * 32;
        mrA0 = mqb[(size_t)sl0 * (NNPX / 2) + mo0 + sm0];
        mrA1 = mqb[(size_t)sl1 * (NNPX / 2) + mo0 + sm1];
        if (t < 160) mrA2 = mqb[(size_t)sl2 * (NNPX / 2) + mo0 + sm2];
    };
    auto STORE = [&](int buf) {
        FSlds[buf][fsw] = fsr;
        ((unsigned int*)Mlds[buf])[mw0] = mrA0;
        ((unsigned int*)Mlds[buf])[mw1] = mrA1;
        if (t < 160) ((unsigned int*)Mlds[buf])[mw2] = mrA2;
    };
    auto COMPUTE = [&](int buf) {
        const float4* FB = (const float4*)FSlds[buf];
        float w[8];
        u32x4 ap;
        #pragma unroll
        for (int j = 0; j < 8; ++j) {
            float4 F = FB[g8 + (j ^ g)];
            w[j] = __builtin_amdgcn_exp2f(F.x + fnx * F.y + fny * F.z + fnz * F.w);
        }
        #pragma unroll
        for (int j = 0; j < 4; ++j) ap[j] = pk_bf16(w[2 * j], w[2 * j + 1]);
        short8 a0 = __builtin_bit_cast(short8, ap);
        #pragma unroll
        for (int j = 0; j < 8; ++j) {
            float4 F = FB[32 + g8 + ((j ^ g) ^ 4)];
            w[j] = __builtin_amdgcn_exp2f(F.x + fnx * F.y + fny * F.z + fnz * F.w);
        }
        #pragma unroll
        for (int j = 0; j < 4; ++j) ap[j] = pk_bf16(w[2 * j], w[2 * j + 1]);
        short8 a1 = __builtin_bit_cast(short8, ap);

        short8 b00 = *(const short8*)&Mlds[buf][ib0];
        short8 b01 = *(const short8*)&Mlds[buf][ib1];
        short8 b10 = *(const short8*)&Mlds[buf][ib2];
        short8 b11 = *(const short8*)&Mlds[buf][ib3];
        acc0 = __builtin_amdgcn_mfma_f32_16x16x32_bf16(a0, b00, acc0, 0, 0, 0);
        acc0 = __builtin_amdgcn_mfma_f32_16x16x32_bf16(a1, b01, acc0, 0, 0, 0);
        acc1 = __builtin_amdgcn_mfma_f32_16x16x32_bf16(a0, b10, acc1, 0, 0, 0);
        acc1 = __builtin_amdgcn_mfma_f32_16x16x32_bf16(a1, b11, acc1, 0, 0, 0);
    };

    // prologue: stage tile 0 into buf 0 (init-stores retired by BARRIER)
    LOAD(0);
    STORE(0);
    BARRIER();

    for (int tt = 0; tt < TT; ++tt) {
        int cur = tt & 1;
        if (tt + 1 < TT) LOAD(tt + 1);
        COMPUTE(cur);
        if (tt + 1 < TT) STORE(cur ^ 1);
        BARRIER();
    }

    // epilogue: C layout col=lane&15, row=(lane>>4)*4+reg
    int col = lane & 15, qr = lane >> 4;
    float* pp = Ppart + ((size_t)(s * BB + b) * LP) * NNPX;
    for (int r = 0; r < 4; ++r) {
        int n = n0 + wv * 16 + qr * 4 + r;
        pp[(size_t)col * NNPX + n] = acc0[r];
        if (col < LP - 16) pp[(size_t)(16 + col) * NNPX + n] = acc1[r];
    }
}

// ------- softmax body: reduce partials + softmax + Potts mix --------------
static __device__ void softmax_body(
        int rb, int t, bool last,
        const float* __restrict__ E0, const float* __restrict__ Ppart,
        const float* __restrict__ Mu,
        __hip_bfloat16* __restrict__ MQ, float* __restrict__ Out) {
    __shared__ float muS_s[LL * LL];
    __shared__ float rsumS_s[64];
    __shared__ float red1_s[4][64], red2_s[4][64];
    __shared__ float Qs_s[LL][64];

    if (!last) for (int i = t; i < LL * LL; i += 256) muS_s[i] = Mu[i];

    int q = t >> 6, px = t & 63;
    int pid = rb * 64 + px;
    int b = pid / NNPX, n = pid % NNPX;

    int l0 = q * 6;
    const float* ppb = Ppart + n;
    const float* eb = E0 + (size_t)b * LL * NNPX + n;

    float Pa[6], e0v[6];
    #pragma unroll
    for (int i = 0; i < 6; ++i) {
        int l = l0 + i;
        Pa[i] = 0.f; e0v[i] = 0.f;
        if (l < LL) {
            for (int s = 0; s < SSPLIT; ++s)
                Pa[i] += ppb[((size_t)(s * BB + b) * LP + l) * NNPX];
            e0v[i] = eb[(size_t)l * NNPX];
        }
    }
    if (q == 3) {
        float racc = 0.f;
        for (int s = 0; s < SSPLIT; ++s)
            racc += ppb[((size_t)(s * BB + b) * LP + LL) * NNPX];
        rsumS_s[px] = racc;
    }
    __syncthreads();
    float rinv = __builtin_amdgcn_rcpf(rsumS_s[px]);

    float x[6];
    float mx = -1e30f;
    #pragma unroll
    for (int i = 0; i < 6; ++i) {
        x[i] = (l0 + i < LL) ? -(e0v[i] + Pa[i] * rinv) : -1e30f;
        mx = fmaxf(mx, x[i]);
    }
    red1_s[q][px] = mx;
    __syncthreads();
    mx = fmaxf(fmaxf(red1_s[0][px], red1_s[1][px]), fmaxf(red1_s[2][px], red1_s[3][px]));
    float ssum = 0.f;
    #pragma unroll
    for (int i = 0; i < 6; ++i) { x[i] = __builtin_amdgcn_exp2f((x[i] - mx) * LOG2E); ssum += x[i]; }
    red2_s[q][px] = ssum;
    __syncthreads();
    float rs = __builtin_amdgcn_rcpf(red2_s[0][px] + red2_s[1][px] + red2_s[2][px] + red2_s[3][px]);

    if (last) {
        float* ob = Out + (size_t)b * LL * NNPX + n;
        #pragma unroll
        for (int i = 0; i < 6; ++i) if (l0 + i < LL) ob[(size_t)(l0 + i) * NNPX] = x[i] * rs;
    } else {
        #pragma unroll
        for (int i = 0; i < 6; ++i) if (l0 + i < LL) Qs_s[l0 + i][px] = x[i] * rs;
        __syncthreads();
        __hip_bfloat16* mq = MQ + (size_t)b * LL * NNPX + n;
        #pragma unroll
        for (int j = 0; j < 6; ++j) {
            int k = l0 + j;
            if (k < LL) {
                float a = 0.f;
                for (int l = 0; l < LL; ++l) a += muS_s[k * LL + l] * Qs_s[l][px];
                mq[(size_t)k * NNPX] = __float2bfloat16(a);
            }
        }
    }
}

// ---------------- fused cooperative kernel ----------------
__global__ __launch_bounds__(256, 4) void k_fused(
        const float* E0, const float* Refs, const float* Mu,
        float4* FS, __hip_bfloat16* MQ, float* Ppart, float* Out) {
    cg::grid_group grid = cg::this_grid();
    int t = threadIdx.x;
    int bx = blockIdx.x;
    int rb = bx % 288;
    int s  = bx / 288;

    if (s == 0) prep_body(rb, t, E0, Refs, Mu, FS, MQ);
    grid.sync();

    for (int it = 0; it < NITERS; ++it) {
        accum_body(rb, s, t, FS, (const unsigned int*)MQ, Ppart);
        grid.sync();
        if (s == 0) softmax_body(rb, t, it == NITERS - 1, E0, Ppart, Mu, MQ, Out);
        grid.sync();
    }
}

// ---------------- fallback separate kernels (same bodies) ----------------
__global__ __launch_bounds__(256) void k_prep_w(
        const float* E0, const float* Refs, const float* Mu,
        float4* FS, __hip_bfloat16* MQ) {
    prep_body(blockIdx.x, threadIdx.x, E0, Refs, Mu, FS, MQ);
}
__global__ __launch_bounds__(256, 4) void k_accum_w(
        const float4* FS, const unsigned int* MQbf, float* Ppart) {
    accum_body(blockIdx.x % 288, blockIdx.x / 288, threadIdx.x, FS, MQbf, Ppart);
}
__global__ __launch_bounds__(256) void k_softmax_w(
        const float* E0, const float* Ppart, const float* Mu,
        __hip_bfloat16* MQ, float* Out, int last) {
    softmax_body(blockIdx.x, threadIdx.x, last != 0, E0, Ppart, Mu, MQ, Out);
}

extern "C" void kernel_launch(void* const* d_in, const int* in_sizes, int n_in,
                              void* d_out, int out_size, void* d_ws, size_t ws_size,
                              hipStream_t stream) {
    const float* E0   = (const float*)d_in[0];
    const float* Refs = (const float*)d_in[1];
    const float* Mu   = (const float*)d_in[2];
    float* out = (float*)d_out;

    char* w = (char*)d_ws;
    size_t off = 0;
    auto alloc = [&](size_t bytes) {
        void* p = w + off;
        off += (bytes + 255) & ~(size_t)255;
        return p;
    };
    float4* FS = (float4*)alloc((size_t)BB * NNPX * sizeof(float4));
    __hip_bfloat16* MQbf = (__hip_bfloat16*)alloc((size_t)BB * LL * NNPX * sizeof(__hip_bfloat16));
    float* Ppart = (float*)alloc((size_t)SSPLIT * BB * LP * NNPX * sizeof(float));

    void* args[] = {(void*)&E0, (void*)&Refs, (void*)&Mu,
                    (void*)&FS, (void*)&MQbf, (void*)&Ppart, (void*)&out};
    hipError_t err = hipLaunchCooperativeKernel(
        (const void*)k_fused, dim3(288 * SSPLIT), dim3(256), args, 0, stream);

    if (err != hipSuccess) {
        // fallback: separate launches, same bodies, same S
        k_prep_w<<<BB * NNPX / 64, 256, 0, stream>>>(E0, Refs, Mu, FS, MQbf);
        for (int it = 0; it < NITERS; ++it) {
            k_accum_w<<<288 * SSPLIT, 256, 0, stream>>>(FS, (const unsigned int*)MQbf, Ppart);
            k_softmax_w<<<BB * NNPX / 64, 256, 0, stream>>>(
                E0, Ppart, Mu, MQbf, out, it == NITERS - 1 ? 1 : 0);
        }
    }
}

// Round 19
// 369.305 us; speedup vs baseline: 3.8686x; 3.8686x over previous
//
#include <hip/hip_runtime.h>
#include <hip/hip_bf16.h>

// CRF-as-RNN mean-field on MI355X. B=2, L=21, C=3, H=W=96, N=9216, NITERS=5.
//
// R12 CHAMPION (lock-in). w[n][m] = exp2(gs[m] + f_n . fs[m]); per iter
// P[n][l] = sum_m w[n][m]*MQ[l][m] via bf16 MFMA 16x16x32.
// k_accum: no W tile — each lane generates its own A-fragment in registers;
// FS staged to LDS (1KB, coalesced) read via conflict-free broadcast
// ds_read_b128 (XOR slot swizzle, proof in COMPUTE); M tile XOR-swizzled
// zero-conflict, const rows 21..31 (row 21 = 1.0 -> MFMA col 21 = rowsum(W)
// free); FS+M double-buffered (10KB), ONE thin lgkm-only barrier per tile;
// depth-1 prefetch. launch_bounds(256,4): grid caps residency at ~4.5
// blocks/CU anyway (R13: forcing 8 spilled).
// Bracketing evidence (rounds 7-18): more LDS traffic (67us), less (110us),
// zero-barrier (110us), atomics (+38MB writes), 2x work/block (65-82us),
// launch_bounds(256,8) (spill), cooperative fusion (1400us!) — all regress.
// VALU 75% + LDS-pipe model ~57us => two-pipe saturation point.
// msg = P/P[21]; Q = softmax_l(-(E0+msg)); MQ = Mu@Q (bf16).

#define BB 2
#define LL 21
#define LP (LL + 1)   // Ppart rows: 21 msg cols + 1 rowsum col
#define NNPX 9216
#define NITERS 5
#define LOG2E 1.4426950408889634f

// raw barrier: waits LDS ops of this wave, syncs, does NOT drain vmcnt
#define BARRIER() asm volatile("s_waitcnt lgkmcnt(0)\n\ts_barrier" ::: "memory")

typedef __attribute__((ext_vector_type(8))) short short8;
typedef __attribute__((ext_vector_type(4))) float f32x4;
typedef __attribute__((ext_vector_type(4))) unsigned int u32x4;

static __device__ inline unsigned int pk_bf16(float a, float b) {
    __hip_bfloat162 h = __float22bfloat162_rn(make_float2(a, b));
    unsigned int u;
    __builtin_memcpy(&u, &h, 4);
    return u;
}

// ---------------- prep: features + Q0 + MQ0(bf16), 4 waves / 64 px ----------
__global__ __launch_bounds__(256) void k_prep(
        const float* __restrict__ E0, const float* __restrict__ Refs,
        const float* __restrict__ Mu,
        float4* __restrict__ FN, float4* __restrict__ FS,
        __hip_bfloat16* __restrict__ MQ) {
    __shared__ float muS[LL * LL];
    __shared__ float red1[4][64], red2[4][64];
    __shared__ float Qs[LL][64];

    int t = threadIdx.x;
    for (int i = t; i < LL * LL; i += 256) muS[i] = Mu[i];

    int q = t >> 6, px = t & 63;
    int pid = blockIdx.x * 64 + px;          // b*N + n (64-tiles never cross b)
    int b = pid / NNPX, n = pid % NNPX;

    if (q == 0) {  // features: one lane per pixel, coalesced
        const float* rb = Refs + (size_t)b * 3 * NNPX + n;
        float r0 = rb[0], r1 = rb[NNPX], r2 = rb[2 * NNPX];
        FN[pid] = make_float4(r0, r1, r2, 0.f);
        float g = -0.5f * (r0 * r0 + r1 * r1 + r2 * r2);
        FS[pid] = make_float4(g * LOG2E, r0 * LOG2E, r1 * LOG2E, r2 * LOG2E);
    }

    int l0 = q * 6;
    const float* eb = E0 + (size_t)b * LL * NNPX + n;
    float x[6];
    float mx = -1e30f;
    #pragma unroll
    for (int i = 0; i < 6; ++i) {
        int l = l0 + i;
        x[i] = (l < LL) ? -eb[(size_t)l * NNPX] : -1e30f;
        mx = fmaxf(mx, x[i]);
    }
    red1[q][px] = mx;
    __syncthreads();
    mx = fmaxf(fmaxf(red1[0][px], red1[1][px]), fmaxf(red1[2][px], red1[3][px]));
    float s = 0.f;
    #pragma unroll
    for (int i = 0; i < 6; ++i) { x[i] = __builtin_amdgcn_exp2f((x[i] - mx) * LOG2E); s += x[i]; }
    red2[q][px] = s;
    __syncthreads();
    float rs = __builtin_amdgcn_rcpf(red2[0][px] + red2[1][px] + red2[2][px] + red2[3][px]);
    #pragma unroll
    for (int i = 0; i < 6; ++i) if (l0 + i < LL) Qs[l0 + i][px] = x[i] * rs;
    __syncthreads();

    __hip_bfloat16* mq = MQ + (size_t)b * LL * NNPX + n;
    #pragma unroll
    for (int j = 0; j < 6; ++j) {
        int k = l0 + j;
        if (k < LL) {
            float a = 0.f;
            for (int l = 0; l < LL; ++l) a += muS[k * LL + l] * Qs[l][px];
            mq[(size_t)k * NNPX] = __float2bfloat16(a);
        }
    }
}

// ---------------- accumulate via MFMA (msg + rowsum fused) ----------------
// grid (288, S): blockIdx.x = b*144 + n-tile (64 rows), blockIdx.y = s.
// Block handles CONTIGUOUS m-tiles [s*T, (s+1)*T), T = 144/S, tiles of 64.
__global__ __launch_bounds__(256, 4) void k_accum(
        const float4* __restrict__ FS, const float4* __restrict__ FN,
        const unsigned int* __restrict__ MQbf, float* __restrict__ Ppart, int S) {
    // FS: 2 x 64 float4 (slot-swizzled, 1KB each). M: 2 x 32x64 bf16
    // (XOR-swizzled, rows 21..31 const). Total 10KB. No W tile.
    __shared__ __align__(16) float FSlds[2][256];
    __shared__ __align__(16) unsigned short Mlds[2][32 * 64];

    int t = threadIdx.x;
    int rb = blockIdx.x;
    int s  = blockIdx.y;
    int b  = rb / 144;
    int n0 = (rb % 144) * 64;
    int wv = t >> 6, lane = t & 63;
    int lr = lane & 15, g = lane >> 4;

    // one-time init of constant B rows in BOTH buffers
    for (int i = t; i < 11 * 32 * 2; i += 256) {
        int bufi = i >= 11 * 32;
        int ii = i - bufi * 11 * 32;
        int r = 21 + (ii >> 5), d = ii & 31;
        ((unsigned int*)&Mlds[bufi][r * 64])[d] = (r == 21) ? 0x3F803F80u : 0u;
    }

    // this thread's A-row feature (row = wv*16 + lr)
    int row = wv * 16 + lr;
    float4 fv = FN[b * NNPX + n0 + row];
    float fnx = fv.x, fny = fv.y, fnz = fv.z;

    const int T  = 144 / S;
    const int t0 = s * T;
    const float* fs32 = (const float*)(FS + (size_t)b * NNPX);
    const unsigned int* mqb = MQbf + (size_t)b * LL * (NNPX / 2);

    // FS stage: thread t loads global dword (m0*4 + t) -> swizzled LDS dword
    int mloc = t >> 2, comp = t & 3;
    int fslot = (mloc & ~7) | ((mloc ^ (mloc >> 3)) & 7);
    int fsw = fslot * 4 + comp;

    // MQ stage ownership (3 dwords) + R11-proven swizzled dests
    int sl0 = t >> 5, sm0 = t & 31;
    int sl1 = (t + 256) >> 5, sm1 = (t + 256) & 31;
    int sl2 = (t + 512) >> 5, sm2 = (t + 512) & 31;   // valid iff t<160
    int mw0 = sl0 * 32 + (((sm0 >> 2) ^ (sl0 & 7)) << 2) + (sm0 & 3);
    int mw1 = sl1 * 32 + (((sm1 >> 2) ^ (sl1 & 7)) << 2) + (sm1 & 3);
    int mw2 = sl2 * 32 + (((sm2 >> 2) ^ (sl2 & 7)) << 2) + (sm2 & 3);

    // B-frag read offsets (R11-proven zero-conflict)
    int ib0 = lr * 64 + ((g ^ (lr & 7)) << 3);
    int ib1 = lr * 64 + (((g + 4) ^ (lr & 7)) << 3);
    int ib2 = (16 + lr) * 64 + ((g ^ (lr & 7)) << 3);
    int ib3 = (16 + lr) * 64 + (((g + 4) ^ (lr & 7)) << 3);

    f32x4 acc0 = {0.f, 0.f, 0.f, 0.f};   // C cols 0..15
    f32x4 acc1 = {0.f, 0.f, 0.f, 0.f};   // C cols 16..21 (22..31 discarded)

    int g8 = g * 8;

    // depth-1 prefetch registers
    float fsr;
    unsigned int mrA0, mrA1, mrA2;

    auto LOAD = [&](int tile) {
        int m0 = (t0 + tile) * 64;
        fsr = fs32[m0 * 4 + t];                        // coalesced 1 dword
        int mo0 = (t0 + tile) * 32;
        mrA0 = mqb[(size_t)sl0 * (NNPX / 2) + mo0 + sm0];
        mrA1 = mqb[(size_t)sl1 * (NNPX / 2) + mo0 + sm1];
        if (t < 160) mrA2 = mqb[(size_t)sl2 * (NNPX / 2) + mo0 + sm2];
    };
    auto STORE = [&](int buf) {
        FSlds[buf][fsw] = fsr;
        ((unsigned int*)Mlds[buf])[mw0] = mrA0;
        ((unsigned int*)Mlds[buf])[mw1] = mrA1;
        if (t < 160) ((unsigned int*)Mlds[buf])[mw2] = mrA2;
    };
    auto COMPUTE = [&](int buf) {
        const float4* FB = (const float4*)FSlds[buf];
        // A-fragment half 0: k-slots m = 8g + j  (swizzled slot 8g + (j^g))
        // broadcast reads: 4 distinct addrs/instr on disjoint bank-quads
        float w[8];
        #pragma unroll
        for (int j = 0; j < 8; ++j) {
            float4 F = FB[g8 + (j ^ g)];
            w[j] = __builtin_amdgcn_exp2f(F.x + fnx * F.y + fny * F.z + fnz * F.w);
        }
        u32x4 ap;
        #pragma unroll
        for (int j = 0; j < 4; ++j) ap[j] = pk_bf16(w[2 * j], w[2 * j + 1]);
        short8 a0 = __builtin_bit_cast(short8, ap);
        // A-fragment half 1: m = 32 + 8g + j  (slot 32 + 8g + ((j^g)^4))
        #pragma unroll
        for (int j = 0; j < 8; ++j) {
            float4 F = FB[32 + g8 + ((j ^ g) ^ 4)];
            w[j] = __builtin_amdgcn_exp2f(F.x + fnx * F.y + fny * F.z + fnz * F.w);
        }
        #pragma unroll
        for (int j = 0; j < 4; ++j) ap[j] = pk_bf16(w[2 * j], w[2 * j + 1]);
        short8 a1 = __builtin_bit_cast(short8, ap);

        short8 b00 = *(const short8*)&Mlds[buf][ib0];
        short8 b01 = *(const short8*)&Mlds[buf][ib1];
        short8 b10 = *(const short8*)&Mlds[buf][ib2];
        short8 b11 = *(const short8*)&Mlds[buf][ib3];
        acc0 = __builtin_amdgcn_mfma_f32_16x16x32_bf16(a0, b00, acc0, 0, 0, 0);
        acc0 = __builtin_amdgcn_mfma_f32_16x16x32_bf16(a1, b01, acc0, 0, 0, 0);
        acc1 = __builtin_amdgcn_mfma_f32_16x16x32_bf16(a0, b10, acc1, 0, 0, 0);
        acc1 = __builtin_amdgcn_mfma_f32_16x16x32_bf16(a1, b11, acc1, 0, 0, 0);
    };

    // ---- prologue: stage tile 0 into buf 0 ----
    LOAD(0);
    STORE(0);
    BARRIER();

    // ---- main loop: ONE thin barrier per tile. Safety: stage(t+1) writes
    // buf^1, whose last readers (compute(t-1)) all finished before the
    // barrier at the end of iteration t-1 (program order + barrier). ----
    for (int tt = 0; tt < T; ++tt) {
        int cur = tt & 1;
        if (tt + 1 < T) LOAD(tt + 1);    // globals in flight across compute
        COMPUTE(cur);
        if (tt + 1 < T) STORE(cur ^ 1);
        BARRIER();
    }

    // epilogue: C layout col=lane&15, row=(lane>>4)*4+reg
    int col = lane & 15, qr = lane >> 4;
    float* pp = Ppart + ((size_t)(s * BB + b) * LP) * NNPX;
    for (int r = 0; r < 4; ++r) {
        int n = n0 + wv * 16 + qr * 4 + r;
        pp[(size_t)col * NNPX + n] = acc0[r];
        if (col < LP - 16) pp[(size_t)(16 + col) * NNPX + n] = acc1[r];
    }
}

// ------- reduce partials + softmax + Potts mix, 4 waves / 64 px -------
template <bool LAST>
__global__ __launch_bounds__(256) void k_softmax(
        const float* __restrict__ E0, const float* __restrict__ Ppart,
        const float* __restrict__ Mu,
        __hip_bfloat16* __restrict__ MQ, float* __restrict__ Out, int S) {
    __shared__ float muS[LL * LL];
    __shared__ float rsumS[64];
    __shared__ float red1[4][64], red2[4][64];
    __shared__ float Qs[LL][64];

    int t = threadIdx.x;
    if (!LAST) for (int i = t; i < LL * LL; i += 256) muS[i] = Mu[i];

    int q = t >> 6, px = t & 63;
    int pid = blockIdx.x * 64 + px;
    int b = pid / NNPX, n = pid % NNPX;

    int l0 = q * 6;
    const float* ppb = Ppart + n;
    const float* eb = E0 + (size_t)b * LL * NNPX + n;

    float Pa[6], e0v[6];
    #pragma unroll
    for (int i = 0; i < 6; ++i) {
        int l = l0 + i;
        Pa[i] = 0.f; e0v[i] = 0.f;
        if (l < LL) {
            for (int s = 0; s < S; ++s)
                Pa[i] += ppb[((size_t)(s * BB + b) * LP + l) * NNPX];
            e0v[i] = eb[(size_t)l * NNPX];
        }
    }
    if (q == 3) {
        float racc = 0.f;
        for (int s = 0; s < S; ++s)
            racc += ppb[((size_t)(s * BB + b) * LP + LL) * NNPX];
        rsumS[px] = racc;
    }
    __syncthreads();
    float rinv = __builtin_amdgcn_rcpf(rsumS[px]);

    float x[6];
    float mx = -1e30f;
    #pragma unroll
    for (int i = 0; i < 6; ++i) {
        x[i] = (l0 + i < LL) ? -(e0v[i] + Pa[i] * rinv) : -1e30f;
        mx = fmaxf(mx, x[i]);
    }
    red1[q][px] = mx;
    __syncthreads();
    mx = fmaxf(fmaxf(red1[0][px], red1[1][px]), fmaxf(red1[2][px], red1[3][px]));
    float ssum = 0.f;
    #pragma unroll
    for (int i = 0; i < 6; ++i) { x[i] = __builtin_amdgcn_exp2f((x[i] - mx) * LOG2E); ssum += x[i]; }
    red2[q][px] = ssum;
    __syncthreads();
    float rs = __builtin_amdgcn_rcpf(red2[0][px] + red2[1][px] + red2[2][px] + red2[3][px]);

    if (LAST) {
        float* ob = Out + (size_t)b * LL * NNPX + n;
        #pragma unroll
        for (int i = 0; i < 6; ++i) if (l0 + i < LL) ob[(size_t)(l0 + i) * NNPX] = x[i] * rs;
    } else {
        #pragma unroll
        for (int i = 0; i < 6; ++i) if (l0 + i < LL) Qs[l0 + i][px] = x[i] * rs;
        __syncthreads();
        __hip_bfloat16* mq = MQ + (size_t)b * LL * NNPX + n;
        #pragma unroll
        for (int j = 0; j < 6; ++j) {
            int k = l0 + j;
            if (k < LL) {
                float a = 0.f;
                for (int l = 0; l < LL; ++l) a += muS[k * LL + l] * Qs[l][px];
                mq[(size_t)k * NNPX] = __float2bfloat16(a);
            }
        }
    }
}

extern "C" void kernel_launch(void* const* d_in, const int* in_sizes, int n_in,
                              void* d_out, int out_size, void* d_ws, size_t ws_size,
                              hipStream_t stream) {
    const float* E0   = (const float*)d_in[0];
    const float* Refs = (const float*)d_in[1];
    const float* Mu   = (const float*)d_in[2];
    float* out = (float*)d_out;

    char* w = (char*)d_ws;
    size_t off = 0;
    auto alloc = [&](size_t bytes) {
        void* p = w + off;
        off += (bytes + 255) & ~(size_t)255;
        return p;
    };
    float4* FN     = (float4*)alloc((size_t)BB * NNPX * sizeof(float4));
    float4* FS     = (float4*)alloc((size_t)BB * NNPX * sizeof(float4));
    __hip_bfloat16* MQbf = (__hip_bfloat16*)alloc((size_t)BB * LL * NNPX * sizeof(__hip_bfloat16));

    // m-split S (divisor of 144, capped at 8) whose partial buffer fits in ws
    size_t per = (size_t)BB * LP * NNPX * sizeof(float);
    size_t avail = ws_size > off ? ws_size - off : 0;
    int Smax = (int)(avail / (per + 256));
    static const int divs[] = {8, 6, 4, 3, 2, 1};
    int S = 1;
    for (int i = 0; i < 6; ++i) if (divs[i] <= Smax) { S = divs[i]; break; }
    float* Ppart = (float*)alloc((size_t)S * per);

    k_prep<<<BB * NNPX / 64, 256, 0, stream>>>(E0, Refs, Mu, FN, FS, MQbf);
    for (int it = 0; it < NITERS; ++it) {
        k_accum<<<dim3(288, S), 256, 0, stream>>>(FS, FN, (const unsigned int*)MQbf, Ppart, S);
        if (it == NITERS - 1)
            k_softmax<true><<<BB * NNPX / 64, 256, 0, stream>>>(E0, Ppart, Mu, MQbf, out, S);
        else
            k_softmax<false><<<BB * NNPX / 64, 256, 0, stream>>>(E0, Ppart, Mu, MQbf, out, S);
    }
}